// Round 1
// baseline (795.755 us; speedup 1.0000x reference)
//
#include <hip/hip_runtime.h>

// SimpleLSTM: 2-layer LSTM (B=512,T=256,F=64,U=128) + Dense(1,relu).
// R9: FUSED both layers into one kernel with a 16-step skew.
//   iter i: cell_A(t=i) and cell_B(t=i-16) are independent -> 272 skewed
//   iterations replace 512 serial steps. h_A passes through an LDS ring
//   (no 32MB global hs round-trip). xz_B = h_A@W2 computed block-wise
//   (M=16 packed, full MFMA util) every 8 iters, double-buffered.
//   Merged epilogue: A outputs in lanes 0-31 (A-rows 0/4), B h fed via
//   A-rows 8/12 so B outputs land in lanes 32-63 -> ONE predicated
//   transcendental chain per lane. W1/W2 frags reloaded at boundaries
//   (L2-hot) to keep hot VGPRs ~240 (uf1+uf2 resident = 128).
// 256 WGs x 512 thr, 2 batch rows/WG, 1 WG/CU (LDS ~141KB).

#define T_STEPS 256
#define BATCH   512
#define NU      128
#define FDIM    64
#define SKEW    16
#define NITER   (T_STEPS + SKEW)   // 272 = 17*16

typedef _Float16 h8 __attribute__((ext_vector_type(8)));
typedef float    f4 __attribute__((ext_vector_type(4)));

#define LOG2E    1.4426950408889634f
#define TWOLOG2E 2.8853900817779268f

// Workgroup barrier draining LDS only (no vmcnt drain; all cross-step deps
// are LDS, global loads wait at use, stores have no in-kernel reader).
#define WG_BARRIER() asm volatile("s_waitcnt lgkmcnt(0)\n\ts_barrier" ::: "memory")

#if __has_builtin(__builtin_amdgcn_exp2f)
#define EXP2F(x) __builtin_amdgcn_exp2f(x)
#else
#define EXP2F(x) exp2f(x)
#endif
#if __has_builtin(__builtin_amdgcn_rcpf)
#define RCPF(x) __builtin_amdgcn_rcpf(x)
#else
#define RCPF(x) (1.0f / (x))
#endif

// s = -z*log2e (sign folded into weights) -> sigmoid(z)
__device__ __forceinline__ float sigm2(float s) {
    return RCPF(1.0f + EXP2F(s));
}
// t = 2*z*log2e -> tanh(z)
__device__ __forceinline__ float tanh2(float t) {
    return 1.0f - 2.0f * RCPF(1.0f + EXP2F(t));
}

// ---- weight prep: col-major [col][k], fp16, fold gate-specific log2e ----
// gates: 0=i 1=f 2=g 3=o ; i/f/o scaled by -log2e (sigm2), g by +2log2e.
__global__ void prep_weights(const float* __restrict__ W1, const float* __restrict__ U1,
                             const float* __restrict__ b1, const float* __restrict__ W2,
                             const float* __restrict__ U2, const float* __restrict__ b2,
                             _Float16* __restrict__ Wp1, _Float16* __restrict__ Up1,
                             _Float16* __restrict__ Wp2, _Float16* __restrict__ Up2,
                             float* __restrict__ bp1, float* __restrict__ bp2) {
    int i = blockIdx.x * 256 + threadIdx.x;
    if (i < 32768) {                       // Wp1 [512][64] from W1 [64][512]
        int col = i >> 6, k = i & 63;
        float sc = ((col >> 7) == 2) ? TWOLOG2E : -LOG2E;
        Wp1[i] = (_Float16)(W1[k * 512 + col] * sc);
    } else if (i < 32768 + 65536) {        // Up1 [512][128] from U1 [128][512]
        int j = i - 32768; int col = j >> 7, k = j & 127;
        float sc = ((col >> 7) == 2) ? TWOLOG2E : -LOG2E;
        Up1[j] = (_Float16)(U1[k * 512 + col] * sc);
    } else if (i < 32768 + 131072) {       // Wp2 [512][128] from W2 [128][512]
        int j = i - 98304; int col = j >> 7, k = j & 127;
        float sc = ((col >> 7) == 2) ? TWOLOG2E : -LOG2E;
        Wp2[j] = (_Float16)(W2[k * 512 + col] * sc);
    } else if (i < 32768 + 196608) {       // Up2 [512][128] from U2 [128][512]
        int j = i - 163840; int col = j >> 7, k = j & 127;
        float sc = ((col >> 7) == 2) ? TWOLOG2E : -LOG2E;
        Up2[j] = (_Float16)(U2[k * 512 + col] * sc);
    } else if (i < 32768 + 196608 + 1024) {
        int j = i - 229376;
        if (j < 512) {
            float sc = ((j >> 7) == 2) ? TWOLOG2E : -LOG2E;
            bp1[j] = b1[j] * sc;
        } else {
            int col = j - 512;
            float sc = ((col >> 7) == 2) ? TWOLOG2E : -LOG2E;
            bp2[col] = b2[col] * sc;
        }
    }
}

// xz LDS layout: [half][r16][u][gate] f32, row stride padded to 516 floats
// (516 = 4 mod 32 dwords -> rows rotate bank groups; 16B-aligned).
#define XROW  516
#define XHALF (16 * XROW)   // 8256 floats = 33,024 B per half
#define PH    136           // h ring row stride in halfs (272 B, 16B-aligned)

__attribute__((amdgpu_waves_per_eu(2, 2)))
__global__ __launch_bounds__(512) void lstm_fused(
    const float* __restrict__ xA,
    const _Float16* __restrict__ Wp1, const _Float16* __restrict__ Up1,
    const _Float16* __restrict__ Wp2, const _Float16* __restrict__ Up2,
    const float* __restrict__ bp1, const float* __restrict__ bp2,
    const float* __restrict__ Wd, const float* __restrict__ bd,
    float* __restrict__ dout) {
    __shared__ __align__(16) float smxzA[2 * XHALF];   // 66,048 B
    __shared__ __align__(16) float smxzB[2 * XHALF];   // 66,048 B
    // h_A ring: 2 blocks x 8 steps x 2 brows = 32 rows; row(t,br)=(t&15)*2+br
    __shared__ __align__(16) _Float16 ringA[32 * PH];  // 8,704 B
    // h_B ring: 2 bufs x 2 brows; read buf tB&1, write buf (tB&1)^1
    __shared__ __align__(16) _Float16 ringB[4 * PH];   // 1,088 B

    const int tid  = threadIdx.x;
    const int lane = tid & 63;
    const int wv   = tid >> 6;       // 0..7, each owns 16 units x 4 gates
    const int m    = lane & 15;
    const int kc   = lane >> 4;      // quad 0..3
    const int u0   = wv * 16;
    const int b0   = blockIdx.x * 2;
    const bool isB = lane >= 32;     // epilogue: lanes 0-31 = cell A, 32-63 = cell B
    const int erow = (lane >> 4) & 1;

    for (int i = tid; i < 32 * PH; i += 512) ringA[i] = (_Float16)0.0f;
    for (int i = tid; i < 4 * PH; i += 512) ringB[i] = (_Float16)0.0f;

    // resident recurrent weight fragments (hot: every step)
    h8 uf1[4][4], uf2[4][4];
#pragma unroll
    for (int g = 0; g < 4; g++)
#pragma unroll
        for (int ks = 0; ks < 4; ks++) {
            uf1[g][ks] = *(const h8*)&Up1[(g * 128 + u0 + m) * 128 + ks * 32 + kc * 8];
            uf2[g][ks] = *(const h8*)&Up2[(g * 128 + u0 + m) * 128 + ks * 32 + kc * 8];
        }
    float biasA[4], biasB[4];
#pragma unroll
    for (int g = 0; g < 4; g++) {
        biasA[g] = bp1[g * 128 + u0 + m];
        biasB[g] = bp2[g * 128 + u0 + m];
    }

    // ---- x-block: packed-M x@W1, 8 steps/block (A-row r16 = s*2 + brow) ----
    f4 rX[4];
    auto loadA = [&](int kblk) {
        int tt = kblk * 8 + (m >> 1); if (tt > T_STEPS - 1) tt = T_STEPS - 1;
        const int bb = b0 + (m & 1);
#pragma unroll
        for (int ks = 0; ks < 2; ks++)
#pragma unroll
            for (int hf = 0; hf < 2; hf++)
                rX[ks * 2 + hf] = *(const f4*)&xA[((size_t)bb * T_STEPS + tt) * FDIM
                                                  + ks * 32 + kc * 8 + hf * 4];
    };
    auto calcXA = [&](int kblk) {       // regs -> smxzA half (kblk&1)
        float* xzw = &smxzA[(kblk & 1) * XHALF];
        f4 accx[4];
#pragma unroll
        for (int g = 0; g < 4; g++) accx[g] = (f4){biasA[g], biasA[g], biasA[g], biasA[g]};
#pragma unroll
        for (int ks = 0; ks < 2; ks++) {
            h8 a;
#pragma unroll
            for (int j = 0; j < 4; j++) {
                a[j]     = (_Float16)rX[ks * 2][j];
                a[4 + j] = (_Float16)rX[ks * 2 + 1][j];
            }
            h8 w[4];   // W1 frags reloaded per boundary (L2-hot, keeps VGPR low)
#pragma unroll
            for (int g = 0; g < 4; g++)
                w[g] = *(const h8*)&Wp1[(g * 128 + u0 + m) * 64 + ks * 32 + kc * 8];
#pragma unroll
            for (int g = 0; g < 4; g++)
                accx[g] = __builtin_amdgcn_mfma_f32_16x16x32_f16(a, w[g], accx[g], 0, 0, 0);
        }
#pragma unroll
        for (int rr = 0; rr < 4; rr++) {
            f4 v = {accx[0][rr], accx[1][rr], accx[2][rr], accx[3][rr]};
            *(f4*)&xzw[(kc * 4 + rr) * XROW + (u0 + m) * 4] = v;
        }
    };
    // xz_B block jb = h_A(block jb) @ W2 + b2, packed M=16 (8 steps x 2 rows).
    // Written at iter 8*(jb+1), consumed at iters 8*jb+16..+23 (double-buffered).
    auto calcXB = [&](int jb) {
        float* xzw = &smxzB[(jb & 1) * XHALF];
        const _Float16* rb = &ringA[((jb & 1) * 16 + (m >> 1) * 2 + (m & 1)) * PH];
        f4 accx[4];
#pragma unroll
        for (int g = 0; g < 4; g++) accx[g] = (f4){biasB[g], biasB[g], biasB[g], biasB[g]};
#pragma unroll
        for (int ks = 0; ks < 4; ks++) {
            h8 a = *(const h8*)&rb[ks * 32 + kc * 8];
            h8 w[4];   // W2 frags reloaded per boundary (L2-hot)
#pragma unroll
            for (int g = 0; g < 4; g++)
                w[g] = *(const h8*)&Wp2[(g * 128 + u0 + m) * 128 + ks * 32 + kc * 8];
#pragma unroll
            for (int g = 0; g < 4; g++)
                accx[g] = __builtin_amdgcn_mfma_f32_16x16x32_f16(a, w[g], accx[g], 0, 0, 0);
        }
#pragma unroll
        for (int rr = 0; rr < 4; rr++) {
            f4 v = {accx[0][rr], accx[1][rr], accx[2][rr], accx[3][rr]};
            *(f4*)&xzw[(kc * 4 + rr) * XROW + (u0 + m) * 4] = v;
        }
    };

    loadA(0); calcXA(0);               // block 0 -> half 0
    loadA(1);                          // in flight for block 1
    __syncthreads();

    const h8 hzero = {};
    h8 ha[4], hb[4];
#pragma unroll
    for (int ks = 0; ks < 4; ks++) { ha[ks] = hzero; hb[ks] = hzero; }

    // loop-invariant zero C for MFMA chain starts (pinned: no per-step remat)
    f4 fzero = (f4){0.f, 0.f, 0.f, 0.f};
    asm volatile("" : "+v"(fzero));

    float cst = 0.0f;                  // c-state: c_A in lanes 0-31, c_B in 32-63

#pragma unroll 16
    for (int i = 0; i < NITER; i++) {
        const int tB = i - SKEW;       // B-cell step (negative => inactive)

        if ((i & 7) == 0) {
            int kn = (i >> 3) + 1;
            if (kn < T_STEPS / 8) {
                calcXA(kn);            // consumes regs loaded 8 iters ago
                loadA(kn + 1);         // issue next block's loads (clamped)
            }
            int jb = (i >> 3) - 1;     // h_A block completed last iter
            if (jb >= 0 && jb < T_STEPS / 8) calcXB(jb);
        }

        // merged xz gate-vector read (A lanes: smxzA, B lanes: smxzB)
        f4 xzv;
        {
            const float* pa = &smxzA[((i  >> 3) & 1) * XHALF + ((i  & 7) * 2 + erow) * XROW + (u0 + m) * 4];
            const float* pb = &smxzB[((tB >> 3) & 1) * XHALF + ((tB & 7) * 2 + erow) * XROW + (u0 + m) * 4];
            xzv = *(const f4*)(isB ? pb : pa);
        }

        // A-frags: h_A(t-1) via A-rows 0/4 (m==0/4) -> C rows 0/4 (lanes 0-31);
        //          h_B(tB-1) via A-rows 8/12 (m==8/12) -> C rows 8/12 (lanes 32-63).
        if ((m & 3) == 0) {
            const int br = (m >> 2) & 1;
            const _Float16* hp = (m & 8)
                ? &ringB[((tB & 1) * 2 + br) * PH]
                : &ringA[(((i - 1) & 15) * 2 + br) * PH];
            h8 f0 = *(const h8*)&hp[0 * 32 + kc * 8];
            h8 f1 = *(const h8*)&hp[1 * 32 + kc * 8];
            h8 f2 = *(const h8*)&hp[2 * 32 + kc * 8];
            h8 f3 = *(const h8*)&hp[3 * 32 + kc * 8];
            if (m & 8) { hb[0] = f0; hb[1] = f1; hb[2] = f2; hb[3] = f3; }
            else       { ha[0] = f0; ha[1] = f1; ha[2] = f2; ha[3] = f3; }
        }

        f4 accA[4], accB[4];
        if (i < T_STEPS) {
#pragma unroll
            for (int g = 0; g < 4; g++)
                accA[g] = __builtin_amdgcn_mfma_f32_16x16x32_f16(ha[0], uf1[g][0], fzero, 0, 0, 0);
#pragma unroll
            for (int ks = 1; ks < 4; ks++)
#pragma unroll
                for (int g = 0; g < 4; g++)
                    accA[g] = __builtin_amdgcn_mfma_f32_16x16x32_f16(ha[ks], uf1[g][ks], accA[g], 0, 0, 0);
        }
        if (tB >= 0) {
#pragma unroll
            for (int g = 0; g < 4; g++)
                accB[g] = __builtin_amdgcn_mfma_f32_16x16x32_f16(hb[0], uf2[g][0], fzero, 0, 0, 0);
#pragma unroll
            for (int ks = 1; ks < 4; ks++)
#pragma unroll
                for (int g = 0; g < 4; g++)
                    accB[g] = __builtin_amdgcn_mfma_f32_16x16x32_f16(hb[ks], uf2[g][ks], accB[g], 0, 0, 0);
        }

        // ONE merged epilogue pass: each lane runs a single cell's chain
        const bool act = isB ? (tB >= 0) : (i < T_STEPS);
        if (act) {
            float zi = (isB ? accB[0][0] : accA[0][0]) + xzv[0];
            float zf = (isB ? accB[1][0] : accA[1][0]) + xzv[1];
            float zg = (isB ? accB[2][0] : accA[2][0]) + xzv[2];
            float zo = (isB ? accB[3][0] : accA[3][0]) + xzv[3];
            float gi = sigm2(zi);
            float gf = sigm2(zf);
            float gg = tanh2(zg);
            float go = sigm2(zo);
            cst = gf * cst + gi * gg;
            float hv = go * tanh2(cst * TWOLOG2E);
            _Float16 h16 = (_Float16)hv;
            _Float16* wp = isB
                ? &ringB[(((tB & 1) ^ 1) * 2 + erow) * PH + u0 + m]
                : &ringA[((i & 15) * 2 + erow) * PH + u0 + m];
            *wp = h16;
        }
        WG_BARRIER();                  // LDS-only drain; vm stays in flight
    }

    // Dense: h_B(255) (tB=255 wrote ringB buf 0, rows 0/1)
    if (wv == 0) {
        int rw = lane >> 5, u = lane & 31;
        float sacc = 0.0f;
#pragma unroll
        for (int j = 0; j < 4; j++) {
            int uu = u + j * 32;
            sacc += (float)ringB[rw * PH + uu] * Wd[uu];
        }
        sacc += __shfl_xor(sacc, 16);
        sacc += __shfl_xor(sacc, 8);
        sacc += __shfl_xor(sacc, 4);
        sacc += __shfl_xor(sacc, 2);
        sacc += __shfl_xor(sacc, 1);
        if ((lane & 31) == 0) dout[b0 + rw] = fmaxf(sacc + bd[0], 0.0f);
    }
}

extern "C" void kernel_launch(void* const* d_in, const int* in_sizes, int n_in,
                              void* d_out, int out_size, void* d_ws, size_t ws_size,
                              hipStream_t stream) {
    const float* x  = (const float*)d_in[0];
    const float* W1 = (const float*)d_in[1];
    const float* U1 = (const float*)d_in[2];
    const float* b1 = (const float*)d_in[3];
    const float* W2 = (const float*)d_in[4];
    const float* U2 = (const float*)d_in[5];
    const float* b2 = (const float*)d_in[6];
    const float* Wd = (const float*)d_in[7];
    const float* bd = (const float*)d_in[8];
    float* out = (float*)d_out;

    const size_t oWp1 = 0;                     // [512][64]  fp16 =  64 KB
    const size_t oUp1 = oWp1 + 65536;          // [512][128] fp16 = 128 KB
    const size_t oWp2 = oUp1 + 131072;
    const size_t oUp2 = oWp2 + 131072;
    const size_t oBp1 = oUp2 + 131072;
    const size_t oBp2 = oBp1 + 2048;
    const size_t need = oBp2 + 2048;           // 462,848 B
    if (ws_size < need) return;

    char* ws = (char*)d_ws;
    _Float16* Wp1 = (_Float16*)(ws + oWp1);
    _Float16* Up1 = (_Float16*)(ws + oUp1);
    _Float16* Wp2 = (_Float16*)(ws + oWp2);
    _Float16* Up2 = (_Float16*)(ws + oUp2);
    float*    bp1 = (float*)(ws + oBp1);
    float*    bp2 = (float*)(ws + oBp2);

    prep_weights<<<900, 256, 0, stream>>>(W1, U1, b1, W2, U2, b2,
                                          Wp1, Up1, Wp2, Up2, bp1, bp2);
    lstm_fused<<<256, 512, 0, stream>>>(x, Wp1, Up1, Wp2, Up2, bp1, bp2,
                                        Wd, bd, out);
}

// Round 2
// 542.908 us; speedup vs baseline: 1.4657x; 1.4657x over previous
//
#include <hip/hip_runtime.h>

// SimpleLSTM: 2-layer LSTM (B=512,T=256,F=64,U=128) + Dense(1,relu).
// R10: fused skewed two-layer kernel (R9 algorithm) with a working register
// plan. R9 failed because 128 VGPRs of resident weights + ~112 other live
// regs made the allocator rematerialize weight loads from global every
// iteration (733MB HBM fetch, L2-bound, 16% MfmaUtil). Fixes:
//  - uf1/uf2 pinned to AGPRs (asm "+a"); MFMA reads B from AGPR natively.
//  - ONE shared A-fragment hab[]: h_A in A-rows 0/4, h_B in A-rows 8/12;
//    the two recurrences differ only in the B operand (uf1 vs uf2).
//  - A-MFMA block -> extract z scalars -> B-MFMA block reusing acc regs.
//  - biases streamed in calcX (L2-hot), blk x 8-step loop (smaller body).
// 256 WGs x 512 thr, 2 batch rows/WG, 1 WG/CU (LDS ~139KB).

#define T_STEPS 256
#define BATCH   512
#define NU      128
#define FDIM    64
#define SKEW    16
#define NITER   (T_STEPS + SKEW)   // 272 = 34*8

typedef _Float16 h8 __attribute__((ext_vector_type(8)));
typedef float    f4 __attribute__((ext_vector_type(4)));

#define LOG2E    1.4426950408889634f
#define TWOLOG2E 2.8853900817779268f

// Workgroup barrier draining LDS only (no vmcnt drain; all cross-step deps
// are LDS, global loads wait at use, stores have no in-kernel reader).
#define WG_BARRIER() asm volatile("s_waitcnt lgkmcnt(0)\n\ts_barrier" ::: "memory")

#if __has_builtin(__builtin_amdgcn_exp2f)
#define EXP2F(x) __builtin_amdgcn_exp2f(x)
#else
#define EXP2F(x) exp2f(x)
#endif
#if __has_builtin(__builtin_amdgcn_rcpf)
#define RCPF(x) __builtin_amdgcn_rcpf(x)
#else
#define RCPF(x) (1.0f / (x))
#endif

// s = -z*log2e (sign folded into weights) -> sigmoid(z)
__device__ __forceinline__ float sigm2(float s) {
    return RCPF(1.0f + EXP2F(s));
}
// t = 2*z*log2e -> tanh(z)
__device__ __forceinline__ float tanh2(float t) {
    return 1.0f - 2.0f * RCPF(1.0f + EXP2F(t));
}

// ---- weight prep: col-major [col][k], fp16, fold gate-specific log2e ----
// gates: 0=i 1=f 2=g 3=o ; i/f/o scaled by -log2e (sigm2), g by +2log2e.
__global__ void prep_weights(const float* __restrict__ W1, const float* __restrict__ U1,
                             const float* __restrict__ b1, const float* __restrict__ W2,
                             const float* __restrict__ U2, const float* __restrict__ b2,
                             _Float16* __restrict__ Wp1, _Float16* __restrict__ Up1,
                             _Float16* __restrict__ Wp2, _Float16* __restrict__ Up2,
                             float* __restrict__ bp1, float* __restrict__ bp2) {
    int i = blockIdx.x * 256 + threadIdx.x;
    if (i < 32768) {                       // Wp1 [512][64] from W1 [64][512]
        int col = i >> 6, k = i & 63;
        float sc = ((col >> 7) == 2) ? TWOLOG2E : -LOG2E;
        Wp1[i] = (_Float16)(W1[k * 512 + col] * sc);
    } else if (i < 32768 + 65536) {        // Up1 [512][128] from U1 [128][512]
        int j = i - 32768; int col = j >> 7, k = j & 127;
        float sc = ((col >> 7) == 2) ? TWOLOG2E : -LOG2E;
        Up1[j] = (_Float16)(U1[k * 512 + col] * sc);
    } else if (i < 32768 + 131072) {       // Wp2 [512][128] from W2 [128][512]
        int j = i - 98304; int col = j >> 7, k = j & 127;
        float sc = ((col >> 7) == 2) ? TWOLOG2E : -LOG2E;
        Wp2[j] = (_Float16)(W2[k * 512 + col] * sc);
    } else if (i < 32768 + 196608) {       // Up2 [512][128] from U2 [128][512]
        int j = i - 163840; int col = j >> 7, k = j & 127;
        float sc = ((col >> 7) == 2) ? TWOLOG2E : -LOG2E;
        Up2[j] = (_Float16)(U2[k * 512 + col] * sc);
    } else if (i < 32768 + 196608 + 1024) {
        int j = i - 229376;
        if (j < 512) {
            float sc = ((j >> 7) == 2) ? TWOLOG2E : -LOG2E;
            bp1[j] = b1[j] * sc;
        } else {
            int col = j - 512;
            float sc = ((col >> 7) == 2) ? TWOLOG2E : -LOG2E;
            bp2[col] = b2[col] * sc;
        }
    }
}

// xz LDS layout: [half][r16][u][gate] f32, row stride padded to 516 floats
// (516 = 4 mod 32 dwords -> rows rotate bank groups; 16B-aligned).
#define XROW  516
#define XHALF (16 * XROW)   // 8256 floats = 33,024 B per half
#define PH    136           // h ring row stride in halfs (272 B, 16B-aligned)

__attribute__((amdgpu_waves_per_eu(2, 2)))
__global__ __launch_bounds__(512) void lstm_fused(
    const float* __restrict__ xA,
    const _Float16* __restrict__ Wp1, const _Float16* __restrict__ Up1,
    const _Float16* __restrict__ Wp2, const _Float16* __restrict__ Up2,
    const float* __restrict__ bp1, const float* __restrict__ bp2,
    const float* __restrict__ Wd, const float* __restrict__ bd,
    float* __restrict__ dout) {
    __shared__ __align__(16) float smxzA[2 * XHALF];   // 66,048 B
    __shared__ __align__(16) float smxzB[2 * XHALF];   // 66,048 B
    // h_A ring: 2 blocks x 8 steps x 2 brows = 32 rows; row(t,br)=(t&15)*2+br
    __shared__ __align__(16) _Float16 ringA[32 * PH];  // 8,704 B
    // h_B ring: 2 bufs x 2 brows; read buf tB&1, write buf (tB&1)^1
    __shared__ __align__(16) _Float16 ringB[4 * PH];   // 1,088 B

    const int tid  = threadIdx.x;
    const int lane = tid & 63;
    const int wv   = tid >> 6;       // 0..7, each owns 16 units x 4 gates
    const int m    = lane & 15;
    const int kc   = lane >> 4;      // quad 0..3
    const int u0   = wv * 16;
    const int b0   = blockIdx.x * 2;
    const bool isB = lane >= 32;     // epilogue: lanes 0-31 = cell A, 32-63 = cell B
    const int erow = (lane >> 4) & 1;

    for (int i = tid; i < 32 * PH; i += 512) ringA[i] = (_Float16)0.0f;
    for (int i = tid; i < 4 * PH; i += 512) ringB[i] = (_Float16)0.0f;

    // resident recurrent weight fragments -> pinned into AGPRs.
    // (128 regs of read-only MFMA-B operands; gfx950 MFMA reads B from AGPR.)
    h8 uf1[4][4], uf2[4][4];
#pragma unroll
    for (int g = 0; g < 4; g++)
#pragma unroll
        for (int ks = 0; ks < 4; ks++) {
            uf1[g][ks] = *(const h8*)&Up1[(g * 128 + u0 + m) * 128 + ks * 32 + kc * 8];
            uf2[g][ks] = *(const h8*)&Up2[(g * 128 + u0 + m) * 128 + ks * 32 + kc * 8];
            asm("" : "+a"(uf1[g][ks]));
            asm("" : "+a"(uf2[g][ks]));
        }

    // ---- x-block: packed-M x@W1, 8 steps/block (A-row r16 = s*2 + brow) ----
    f4 rX[4];
    auto loadA = [&](int kblk) {
        int tt = kblk * 8 + (m >> 1); if (tt > T_STEPS - 1) tt = T_STEPS - 1;
        const int bb = b0 + (m & 1);
#pragma unroll
        for (int ks = 0; ks < 2; ks++)
#pragma unroll
            for (int hf = 0; hf < 2; hf++)
                rX[ks * 2 + hf] = *(const f4*)&xA[((size_t)bb * T_STEPS + tt) * FDIM
                                                  + ks * 32 + kc * 8 + hf * 4];
    };
    auto calcXA = [&](int kblk) {       // regs -> smxzA half (kblk&1)
        float* xzw = &smxzA[(kblk & 1) * XHALF];
        f4 accx[4];
#pragma unroll
        for (int g = 0; g < 4; g++) {
            float bs = bp1[g * 128 + u0 + m];    // streamed, L2-hot
            accx[g] = (f4){bs, bs, bs, bs};
        }
#pragma unroll
        for (int ks = 0; ks < 2; ks++) {
            h8 a;
#pragma unroll
            for (int j = 0; j < 4; j++) {
                a[j]     = (_Float16)rX[ks * 2][j];
                a[4 + j] = (_Float16)rX[ks * 2 + 1][j];
            }
            h8 w[4];   // W1 frags streamed per boundary (L2-hot)
#pragma unroll
            for (int g = 0; g < 4; g++)
                w[g] = *(const h8*)&Wp1[(g * 128 + u0 + m) * 64 + ks * 32 + kc * 8];
#pragma unroll
            for (int g = 0; g < 4; g++)
                accx[g] = __builtin_amdgcn_mfma_f32_16x16x32_f16(a, w[g], accx[g], 0, 0, 0);
        }
#pragma unroll
        for (int rr = 0; rr < 4; rr++) {
            f4 v = {accx[0][rr], accx[1][rr], accx[2][rr], accx[3][rr]};
            *(f4*)&xzw[(kc * 4 + rr) * XROW + (u0 + m) * 4] = v;
        }
    };
    // xz_B block jb = h_A(block jb) @ W2 + b2, packed M=16 (8 steps x 2 rows).
    // Issued at blk=jb+1 boundary, consumed at blk=jb+2 (double-buffered).
    auto calcXB = [&](int jb) {
        float* xzw = &smxzB[(jb & 1) * XHALF];
        const _Float16* rb = &ringA[((jb & 1) * 16 + (m >> 1) * 2 + (m & 1)) * PH];
        f4 accx[4];
#pragma unroll
        for (int g = 0; g < 4; g++) {
            float bs = bp2[g * 128 + u0 + m];    // streamed, L2-hot
            accx[g] = (f4){bs, bs, bs, bs};
        }
#pragma unroll
        for (int ks = 0; ks < 4; ks++) {
            h8 a = *(const h8*)&rb[ks * 32 + kc * 8];
            h8 w[4];   // W2 frags streamed per boundary (L2-hot)
#pragma unroll
            for (int g = 0; g < 4; g++)
                w[g] = *(const h8*)&Wp2[(g * 128 + u0 + m) * 128 + ks * 32 + kc * 8];
#pragma unroll
            for (int g = 0; g < 4; g++)
                accx[g] = __builtin_amdgcn_mfma_f32_16x16x32_f16(a, w[g], accx[g], 0, 0, 0);
        }
#pragma unroll
        for (int rr = 0; rr < 4; rr++) {
            f4 v = {accx[0][rr], accx[1][rr], accx[2][rr], accx[3][rr]};
            *(f4*)&xzw[(kc * 4 + rr) * XROW + (u0 + m) * 4] = v;
        }
    };

    loadA(0); calcXA(0);               // block 0 -> half 0
    loadA(1);                          // in flight for block 1
    __syncthreads();

    // shared A-fragment: h_A(t-1) in A-rows 0/4 (m==0/4, from ringA),
    // h_B(tB-1) in A-rows 8/12 (m==8/12, from ringB). Both recurrences use
    // the SAME hab; only the B operand differs (uf1 vs uf2).
    h8 hab[4];
    const h8 hzero = {};
#pragma unroll
    for (int ks = 0; ks < 4; ks++) hab[ks] = hzero;

    // loop-invariant zero C for MFMA chain starts (pinned: no per-step remat)
    f4 fzero = (f4){0.f, 0.f, 0.f, 0.f};
    asm volatile("" : "+v"(fzero));

    float cst = 0.0f;                  // c-state: c_A in lanes 0-31, c_B in 32-63

    float* xzsel = isB ? smxzB : smxzA;  // both lanes' xz share parity+row index

    for (int blk = 0; blk < NITER / 8; ++blk) {
        {   // boundary work, once per 8 iters (after previous blk's barrier)
            const int kn = blk + 1;
            if (kn < T_STEPS / 8) {
                calcXA(kn);            // consumes regs loaded 8 iters ago
                loadA(kn + 1);         // issue next block's loads (clamped)
            }
            const int jb = blk - 1;    // h_A block completed last iter
            if (jb >= 0 && jb < T_STEPS / 8) calcXB(jb);
        }
#pragma unroll
        for (int s = 0; s < 8; ++s) {
            // xz gate-vector: A lanes read smxzA, B lanes smxzB; the half
            // parity and row index coincide ((tB>>3)&1 == blk&1, tB&7 == s).
            f4 xzv = *(const f4*)&xzsel[(blk & 1) * XHALF
                                        + (s * 2 + erow) * XROW + (u0 + m) * 4];

            if ((m & 3) == 0) {
                const int br = (m >> 2) & 1;
                const _Float16* hp;
                if (m & 8) {
                    hp = &ringB[((s & 1) * 2 + br) * PH];     // read buf = tB&1 = s&1
                } else {
                    const int rprev = (blk * 8 + s - 1) & 15; // h_A(t-1) row
                    hp = &ringA[(rprev * 2 + br) * PH];
                }
#pragma unroll
                for (int ks = 0; ks < 4; ks++)
                    hab[ks] = *(const h8*)&hp[ks * 32 + kc * 8];
            }

            float z0 = 0.f, z1 = 0.f, z2 = 0.f, z3 = 0.f;
            if (blk < T_STEPS / 8) {           // layer A active (i < 256)
                f4 acc[4];
#pragma unroll
                for (int g = 0; g < 4; g++)
                    acc[g] = __builtin_amdgcn_mfma_f32_16x16x32_f16(hab[0], uf1[g][0], fzero, 0, 0, 0);
#pragma unroll
                for (int ks = 1; ks < 4; ks++)
#pragma unroll
                    for (int g = 0; g < 4; g++)
                        acc[g] = __builtin_amdgcn_mfma_f32_16x16x32_f16(hab[ks], uf1[g][ks], acc[g], 0, 0, 0);
                z0 = acc[0][0] + xzv[0];
                z1 = acc[1][0] + xzv[1];
                z2 = acc[2][0] + xzv[2];
                z3 = acc[3][0] + xzv[3];
            }
            if (blk >= 2) {                    // layer B active (tB >= 0)
                f4 acc[4];
#pragma unroll
                for (int g = 0; g < 4; g++)
                    acc[g] = __builtin_amdgcn_mfma_f32_16x16x32_f16(hab[0], uf2[g][0], fzero, 0, 0, 0);
#pragma unroll
                for (int ks = 1; ks < 4; ks++)
#pragma unroll
                    for (int g = 0; g < 4; g++)
                        acc[g] = __builtin_amdgcn_mfma_f32_16x16x32_f16(hab[ks], uf2[g][ks], acc[g], 0, 0, 0);
                if (isB) {
                    z0 = acc[0][0] + xzv[0];
                    z1 = acc[1][0] + xzv[1];
                    z2 = acc[2][0] + xzv[2];
                    z3 = acc[3][0] + xzv[3];
                }
            }

            // ONE merged epilogue pass: each lane runs a single cell's chain
            const bool act = isB ? (blk >= 2) : (blk < T_STEPS / 8);
            if (act) {
                float gi = sigm2(z0);
                float gf = sigm2(z1);
                float gg = tanh2(z2);
                float go = sigm2(z3);
                cst = gf * cst + gi * gg;
                float hv = go * tanh2(cst * TWOLOG2E);
                _Float16 h16 = (_Float16)hv;
                _Float16* wp;
                if (isB) {
                    wp = &ringB[((((s & 1) ^ 1)) * 2 + erow) * PH + u0 + m];
                } else {
                    const int rcur = (blk & 1) * 8 + s;       // i & 15
                    wp = &ringA[(rcur * 2 + erow) * PH + u0 + m];
                }
                *wp = h16;
            }
            WG_BARRIER();              // LDS-only drain; vm stays in flight
        }
    }

    // Dense: h_B(255) (tB=255, s=7 wrote ringB buf 0, rows 0/1)
    if (wv == 0) {
        int rw = lane >> 5, u = lane & 31;
        float sacc = 0.0f;
#pragma unroll
        for (int j = 0; j < 4; j++) {
            int uu = u + j * 32;
            sacc += (float)ringB[rw * PH + uu] * Wd[uu];
        }
        sacc += __shfl_xor(sacc, 16);
        sacc += __shfl_xor(sacc, 8);
        sacc += __shfl_xor(sacc, 4);
        sacc += __shfl_xor(sacc, 2);
        sacc += __shfl_xor(sacc, 1);
        if ((lane & 31) == 0) dout[b0 + rw] = fmaxf(sacc + bd[0], 0.0f);
    }
}

extern "C" void kernel_launch(void* const* d_in, const int* in_sizes, int n_in,
                              void* d_out, int out_size, void* d_ws, size_t ws_size,
                              hipStream_t stream) {
    const float* x  = (const float*)d_in[0];
    const float* W1 = (const float*)d_in[1];
    const float* U1 = (const float*)d_in[2];
    const float* b1 = (const float*)d_in[3];
    const float* W2 = (const float*)d_in[4];
    const float* U2 = (const float*)d_in[5];
    const float* b2 = (const float*)d_in[6];
    const float* Wd = (const float*)d_in[7];
    const float* bd = (const float*)d_in[8];
    float* out = (float*)d_out;

    const size_t oWp1 = 0;                     // [512][64]  fp16 =  64 KB
    const size_t oUp1 = oWp1 + 65536;          // [512][128] fp16 = 128 KB
    const size_t oWp2 = oUp1 + 131072;
    const size_t oUp2 = oWp2 + 131072;
    const size_t oBp1 = oUp2 + 131072;
    const size_t oBp2 = oBp1 + 2048;
    const size_t need = oBp2 + 2048;           // 462,848 B
    if (ws_size < need) return;

    char* ws = (char*)d_ws;
    _Float16* Wp1 = (_Float16*)(ws + oWp1);
    _Float16* Up1 = (_Float16*)(ws + oUp1);
    _Float16* Wp2 = (_Float16*)(ws + oWp2);
    _Float16* Up2 = (_Float16*)(ws + oUp2);
    float*    bp1 = (float*)(ws + oBp1);
    float*    bp2 = (float*)(ws + oBp2);

    prep_weights<<<900, 256, 0, stream>>>(W1, U1, b1, W2, U2, b2,
                                          Wp1, Up1, Wp2, Up2, bp1, bp2);
    lstm_fused<<<256, 512, 0, stream>>>(x, Wp1, Up1, Wp2, Up2, bp1, bp2,
                                        Wd, bd, out);
}